// Round 6
// baseline (222.482 us; speedup 1.0000x reference)
//
#include <hip/hip_runtime.h>
#include <hip/hip_bf16.h>
#include <math.h>

typedef __bf16 bf16;
typedef __bf16 bf16x4 __attribute__((ext_vector_type(4)));
typedef __bf16 bf16x8 __attribute__((ext_vector_type(8)));
typedef float  f32x4  __attribute__((ext_vector_type(4)));

#define N_PTS 32768

// ---------------- standalone per-point classify (fallback path only) ----------------
__global__ void k_point(const float* __restrict__ pts, float* __restrict__ out,
                        int* __restrict__ counts, unsigned short* __restrict__ idxlist) {
    __shared__ int lcnt[8], lbase[8];
    int t = threadIdx.x;
    int n = blockIdx.x * 256 + t;
    if (t < 8) lcnt[t] = 0;
    __syncthreads();
    float px = pts[3*n+0], py = pts[3*n+1], pz = pts[3*n+2];
    int e = 0; float best = 3.4e38f;
    #pragma unroll
    for (int i = 0; i < 4; ++i)
        #pragma unroll
        for (int j = 0; j < 2; ++j) {
            float cx = j ? 50.f : -50.f, cy = -75.f + 50.f * i;
            float dx = px - cx, dy = py - cy, dz = pz - 20.f;
            float d = dx*dx + dy*dy + dz*dz;
            if (d < best) { best = d; e = i*2 + j; }   // first-min tie-break = np argmin
        }
    bool fg = (px >= -80.f && px <= 80.f && py >= -80.f && py <= 80.f &&
               pz >= -4.f  && pz <= 44.f);
    int slot = -1;
    if (fg) {
        slot = atomicAdd(&lcnt[e], 1);          // LDS atomic: cheap
    } else {
        out[n] = 0.f;
        out[N_PTS + 3*n + 0] = 0.f;
        out[N_PTS + 3*n + 1] = 0.f;
        out[N_PTS + 3*n + 2] = 0.f;
    }
    __syncthreads();
    if (t < 8) lbase[t] = atomicAdd(&counts[t], lcnt[t]);   // 8 global atomics per block
    __syncthreads();
    if (slot >= 0) idxlist[e * N_PTS + lbase[e] + slot] = (unsigned short)n;
}

// ---------------- merged: vectorized weight pre-pack (y=0..5) + classify (y=6) ----------------
__global__ void k_tp(const float* __restrict__ s0, const float* __restrict__ s1,
                     const float* __restrict__ s2, const float* __restrict__ s3,
                     const float* __restrict__ s4, const float* __restrict__ s5,
                     bf16* __restrict__ d0, bf16* __restrict__ d1, bf16* __restrict__ d2,
                     bf16* __restrict__ d3, bf16* __restrict__ d4, bf16* __restrict__ d5,
                     const float* __restrict__ pts, float* __restrict__ out,
                     int* __restrict__ counts, unsigned short* __restrict__ idxlist) {
    int t = threadIdx.x;
    if (blockIdx.y == 6) {
        __shared__ int lcnt[8], lbase[8];
        if (blockIdx.x >= N_PTS / 256) return;
        int n = blockIdx.x * 256 + t;
        if (t < 8) lcnt[t] = 0;
        __syncthreads();
        float px = pts[3*n+0], py = pts[3*n+1], pz = pts[3*n+2];
        int e = 0; float best = 3.4e38f;
        #pragma unroll
        for (int i = 0; i < 4; ++i)
            #pragma unroll
            for (int j = 0; j < 2; ++j) {
                float cx = j ? 50.f : -50.f, cy = -75.f + 50.f * i;
                float dx = px - cx, dy = py - cy, dz = pz - 20.f;
                float d = dx*dx + dy*dy + dz*dz;
                if (d < best) { best = d; e = i*2 + j; }
            }
        bool fg = (px >= -80.f && px <= 80.f && py >= -80.f && py <= 80.f &&
                   pz >= -4.f  && pz <= 44.f);
        int slot = -1;
        if (fg) {
            slot = atomicAdd(&lcnt[e], 1);
        } else {
            out[n] = 0.f;
            out[N_PTS + 3*n + 0] = 0.f;
            out[N_PTS + 3*n + 1] = 0.f;
            out[N_PTS + 3*n + 2] = 0.f;
        }
        __syncthreads();
        if (t < 8) lbase[t] = atomicAdd(&counts[t], lcnt[t]);
        __syncthreads();
        if (slot >= 0) idxlist[e * N_PTS + lbase[e] + slot] = (unsigned short)n;
        return;
    }
    __shared__ bf16 tile[64 * 68];
    const float* src; bf16* dst; int K, Nn, Kpad, Eg;
    switch (blockIdx.y) {
        case 0:  src = s0; dst = d0; K = 111; Nn = 256; Kpad = 128; Eg = 8;  break; // W0
        case 1:  src = s1; dst = d1; K = 256; Nn = 256; Kpad = 256; Eg = 24; break; // W_pre
        case 2:  src = s2; dst = d2; K = 367; Nn = 256; Kpad = 384; Eg = 8;  break; // Wskip
        case 3:  src = s3; dst = d3; K = 256; Nn = 256; Kpad = 256; Eg = 24; break; // W_post
        case 4:  src = s4; dst = d4; K = 256; Nn = 256; Kpad = 256; Eg = 8;  break; // Wf
        default: src = s5; dst = d5; K = 283; Nn = 128; Kpad = 288; Eg = 8;  break; // Wc1
    }
    int ktiles = (Kpad + 63) / 64, ntiles = Nn / 64;
    int b = blockIdx.x;
    if (b >= Eg * ktiles * ntiles) return;
    int eg = b / (ktiles * ntiles), rem = b % (ktiles * ntiles);
    int kt = rem / ntiles, nt = rem % ntiles;
    #pragma unroll
    for (int r = 0; r < 4; ++r) {
        int idx = r * 256 + t;
        int kl = idx >> 4, nl4 = (idx & 15) * 4;
        int kg = kt * 64 + kl, ng = nt * 64 + nl4;
        bf16x4 v = (bf16x4){(bf16)0.f, (bf16)0.f, (bf16)0.f, (bf16)0.f};
        if (kg < K) {
            f32x4 f = *(const f32x4*)(src + ((size_t)(eg * K + kg)) * Nn + ng);
            v[0] = (bf16)f[0]; v[1] = (bf16)f[1]; v[2] = (bf16)f[2]; v[3] = (bf16)f[3];
        }
        *(bf16x4*)(&tile[kl * 68 + nl4]) = v;
    }
    __syncthreads();
    #pragma unroll
    for (int i = 0; i < 2; ++i) {
        int idx = i * 256 + t;
        int ng_l = idx >> 3, kq = idx & 7;
        int kg = kt * 64 + kq * 8, ng = nt * 64 + ng_l;
        if (kg < Kpad) {
            bf16x8 v;
            #pragma unroll
            for (int j = 0; j < 8; ++j) v[j] = tile[(kq * 8 + j) * 68 + ng_l];
            *(bf16x8*)(dst + ((size_t)(eg * Nn + ng)) * Kpad + kg) = v;
        }
    }
}

// ---------------- fused MLP: 32 pts/block, 512 threads (8 waves x n=32), MFMA 16x16x32 ----------------
__device__ __forceinline__ f32x4 mfma16(bf16x8 a, bf16x8 b, f32x4 c) {
    return __builtin_amdgcn_mfma_f32_16x16x32_bf16(a, b, c, 0, 0, 0);
}

__device__ __forceinline__ void zacc(f32x4 acc[2][2]) {
    #pragma unroll
    for (int i = 0; i < 2; ++i)
        #pragma unroll
        for (int j = 0; j < 2; ++j) acc[i][j] = (f32x4){0.f, 0.f, 0.f, 0.f};
}

// Cross-barrier B-prefetch: next layer's first-4 K-step fragments (8 x bf16x8 = 32 VGPR).
// Weight loads depend on nothing -> issue them BEFORE the layer barrier so their
// latency resolves under epilogue + barrier + next-layer A-reads (convoy dead time).
template<int KPAD>
__device__ __forceinline__ void ldpf(bf16x8 pf[8], const bf16* __restrict__ Wt, int wk0,
                                     int nbase, int l16, int quad) {
    #pragma unroll
    for (int s = 0; s < 4; ++s) {
        int kA = s * 32 + quad * 8;
        pf[s * 2]     = *(const bf16x8*)(Wt + (size_t)(nbase +      l16) * KPAD + wk0 + kA);
        pf[s * 2 + 1] = *(const bf16x8*)(Wt + (size_t)(nbase + 16 + l16) * KPAD + wk0 + kA);
    }
}

// PACKED gemm consuming prefetched fragments for s=0..3, inline loads for s=4..NS-1
template<int NS, int KPAD>
__device__ __forceinline__ void gemm_pf(f32x4 acc[2][2], const bf16* A, int astr,
                                        const bf16x8 (&pf)[8],
                                        const bf16* __restrict__ Wt, int wk0,
                                        int nbase, int l16, int quad) {
    #pragma unroll
    for (int s = 0; s < NS; ++s) {
        int kA = s * 32 + quad * 8;
        bf16x8 a0 = *(const bf16x8*)(A + (size_t)(l16)      * astr + kA);
        bf16x8 a1 = *(const bf16x8*)(A + (size_t)(16 + l16) * astr + kA);
        bf16x8 b0, b1;
        if (s < 4) { b0 = pf[s * 2]; b1 = pf[s * 2 + 1]; }
        else {
            b0 = *(const bf16x8*)(Wt + (size_t)(nbase +      l16) * KPAD + wk0 + kA);
            b1 = *(const bf16x8*)(Wt + (size_t)(nbase + 16 + l16) * KPAD + wk0 + kA);
        }
        acc[0][0] = mfma16(a0, b0, acc[0][0]);
        acc[1][0] = mfma16(a1, b0, acc[1][0]);
        acc[0][1] = mfma16(a0, b1, acc[0][1]);
        acc[1][1] = mfma16(a1, b1, acc[1][1]);
    }
}

// PACKED, no prefetch (secondary K-segments: skip's x0 part, c1's de part)
template<int NS, int KPAD>
__device__ __forceinline__ void gemm_p(f32x4 acc[2][2], const bf16* A, int astr,
                                       const bf16* __restrict__ Wt, int wk0,
                                       int nbase, int l16, int quad) {
    #pragma unroll
    for (int s = 0; s < NS; ++s) {
        int kA = s * 32 + quad * 8;
        bf16x8 a0 = *(const bf16x8*)(A + (size_t)(l16)      * astr + kA);
        bf16x8 a1 = *(const bf16x8*)(A + (size_t)(16 + l16) * astr + kA);
        bf16x8 b0 = *(const bf16x8*)(Wt + (size_t)(nbase +      l16) * KPAD + wk0 + kA);
        bf16x8 b1 = *(const bf16x8*)(Wt + (size_t)(nbase + 16 + l16) * KPAD + wk0 + kA);
        acc[0][0] = mfma16(a0, b0, acc[0][0]);
        acc[1][0] = mfma16(a1, b0, acc[1][0]);
        acc[0][1] = mfma16(a0, b1, acc[0][1]);
        acc[1][1] = mfma16(a1, b1, acc[1][1]);
    }
}

// DIRECT fallback (ws too small): strided f32 loads
template<int NS, bool GUARD>
__device__ __forceinline__ void gemm_g(f32x4 acc[2][2], const bf16* A, int astr,
                                       const float* __restrict__ W, int ldn, int wk0, int Klim,
                                       int nbase, int l16, int quad) {
    #pragma unroll
    for (int s = 0; s < NS; ++s) {
        int kA = s * 32 + quad * 8;
        bf16x8 a0 = *(const bf16x8*)(A + (size_t)(l16)      * astr + kA);
        bf16x8 a1 = *(const bf16x8*)(A + (size_t)(16 + l16) * astr + kA);
        #pragma unroll
        for (int nt = 0; nt < 2; ++nt) {
            int n = nbase + nt * 16 + l16;
            const float* wp = W + (size_t)(wk0 + kA) * ldn + n;
            bf16x8 b;
            #pragma unroll
            for (int j = 0; j < 8; ++j) {
                float wv = 0.f;
                if (!GUARD || (wk0 + kA + j < Klim)) wv = wp[(size_t)j * ldn];
                b[j] = (bf16)wv;
            }
            acc[0][nt] = mfma16(a0, b, acc[0][nt]);
            acc[1][nt] = mfma16(a1, b, acc[1][nt]);
        }
    }
}

__device__ __forceinline__ void epi(f32x4 acc[2][2], const float* bias, bool dorelu,
                                    bf16* dst, int dstr, int nbase, int l16, int quad) {
    #pragma unroll
    for (int nt = 0; nt < 2; ++nt) {
        float bv = bias[nbase + nt * 16 + l16];
        #pragma unroll
        for (int mt = 0; mt < 2; ++mt) {
            #pragma unroll
            for (int r = 0; r < 4; ++r) {
                float v = acc[mt][nt][r] + bv;
                v = fminf(fmaxf(v, -64.f), 64.f);
                if (dorelu) v = fmaxf(v, 0.f);
                // C/D layout: col(n)=lane&15, row(m)=quad*4+r  [measured m89/m91]
                dst[(size_t)(mt * 16 + quad * 4 + r) * dstr + nbase + nt * 16 + l16] = (bf16)v;
            }
        }
    }
}

template<bool PACKED>
__global__ __launch_bounds__(512, 2)
void k_main(const int* __restrict__ counts, const unsigned short* __restrict__ idxlist,
            const float* __restrict__ pts, const float* __restrict__ dirs,
            const float* __restrict__ app_embed, const int* __restrict__ aidx,
            const float* __restrict__ W0, const float* __restrict__ b0,
            const float* __restrict__ W_pre, const float* __restrict__ b_pre,
            const float* __restrict__ Wskip, const float* __restrict__ bskip,
            const float* __restrict__ W_post, const float* __restrict__ b_post,
            const float* __restrict__ Wd, const float* __restrict__ bd,
            const float* __restrict__ Wf, const float* __restrict__ bf_,
            const float* __restrict__ Wc1, const float* __restrict__ bc1,
            const float* __restrict__ Wc2, const float* __restrict__ bc2,
            const bf16* __restrict__ wt0, const bf16* __restrict__ wtpre,
            const bf16* __restrict__ wtskip, const bf16* __restrict__ wtpost,
            const bf16* __restrict__ wtf, const bf16* __restrict__ wtc1,
            float* __restrict__ out) {
    __shared__ bf16 xaA[32 * 264];
    __shared__ bf16 xaB[32 * 264];
    __shared__ bf16 x0l[32 * 136];
    __shared__ bf16 del[32 * 48];
    __shared__ int  gidx[32];
    __shared__ int  aid[32];

    const int e    = blockIdx.x & 7;       // expert -> XCD affinity (per-expert 1.23 MB packed weights L2-resident)
    const int tile = blockIdx.x >> 3;
    const int cnt  = counts[e];
    if (tile * 32 >= cnt) return;
    const int t = threadIdx.x;
    const int lane = t & 63, wv = t >> 6;          // 8 waves
    const int l16 = lane & 15, quad = lane >> 4;
    const int nbase = wv * 32;                     // 32 outputs per wave

    f32x4  acc[2][2];
    bf16x8 pf[8];
    // issue L0's B-prefetch NOW: ~3K cycles of sin/cos staging cover its latency
    if (PACKED) ldpf<128>(pf, wt0 + (size_t)e * 32768, 0, nbase, l16, quad);

    if (t < 32) {
        int i = tile * 32 + t;
        int g = (i < cnt) ? (int)idxlist[e * N_PTS + i] : -1;
        gidx[t] = g;
        aid[t]  = (g >= 0) ? aidx[g] : 0;
    }
    __syncthreads();
    { // stage x0 = [p(3), posenc(60), app(48), 0-pad->128] and de = [d(3), posenc(24), 0-pad->32]
        int row = t >> 4, c0 = t & 15, g = gidx[row];
        float p0 = 0.f, p1 = 0.f, p2 = 0.f, q0 = 0.f, q1 = 0.f, q2 = 0.f;
        if (g >= 0) {
            p0 = pts[3*g+0];  p1 = pts[3*g+1];  p2 = pts[3*g+2];
            q0 = dirs[3*g+0]; q1 = dirs[3*g+1]; q2 = dirs[3*g+2];
        }
        int ai = aid[row];
        #pragma unroll
        for (int i = 0; i < 8; ++i) {
            int col = c0 + 16 * i;             // 0..127
            float v = 0.f;
            if (g >= 0 && col < 111) {
                if (col < 3) {
                    v = (col == 0) ? p0 : (col == 1) ? p1 : p2;
                } else if (col < 63) {
                    int q = col - 3, fi = q / 6, d = q % 6, ax = (d < 3) ? d : (d - 3);
                    float p = (ax == 0) ? p0 : (ax == 1) ? p1 : p2;
                    float f = (float)exp2((double)fi * (10.0 / 9.0)); // np 2**linspace(0,10,10)
                    v = (d < 3) ? sinf(f * p) : cosf(f * p);
                } else {
                    v = app_embed[((size_t)(e * 1000 + ai)) * 48 + (col - 63)];
                }
            }
            x0l[row * 136 + col] = (bf16)v;
        }
        #pragma unroll
        for (int i = 0; i < 2; ++i) {
            int col = c0 + 16 * i;             // 0..31
            float v = 0.f;
            if (g >= 0 && col < 27) {
                if (col < 3) {
                    v = (col == 0) ? q0 : (col == 1) ? q1 : q2;
                } else {
                    int q = col - 3, fi = q / 6, d = q % 6, ax = (d < 3) ? d : (d - 3);
                    float p = (ax == 0) ? q0 : (ax == 1) ? q1 : q2;
                    float f = (float)exp2((double)fi * (4.0 / 3.0));  // np 2**linspace(0,4,4)
                    v = (d < 3) ? sinf(f * p) : cosf(f * p);
                }
            }
            del[row * 48 + col] = (bf16)v;
        }
    }
    __syncthreads();

    // L0: x0 -> xaA   (B fully prefetched; issue pre0's prefetch before the barrier)
    zacc(acc);
    if (PACKED) {
        gemm_pf<4, 128>(acc, x0l, 136, pf, wt0 + (size_t)e * 32768, 0, nbase, l16, quad);
        ldpf<256>(pf, wtpre + (size_t)(e * 3) * 65536, 0, nbase, l16, quad);
    } else {
        gemm_g<4, true>(acc, x0l, 136, W0 + (size_t)e * 28416, 256, 0, 111, nbase, l16, quad);
    }
    epi(acc, b0 + e * 256, true, xaA, 264, nbase, l16, quad);
    __syncthreads();
    // pre0: A->B ; pre1: B->A ; pre2: A->B
    #pragma unroll
    for (int i = 0; i < 3; ++i) {
        const bf16* src = (i & 1) ? xaB : xaA;
        bf16*       dst = (i & 1) ? xaA : xaB;
        zacc(acc);
        if (PACKED) {
            gemm_pf<8, 256>(acc, src, 264, pf, wtpre + (size_t)(e * 3 + i) * 65536, 0, nbase, l16, quad);
            if (i < 2) ldpf<256>(pf, wtpre + (size_t)(e * 3 + i + 1) * 65536, 0, nbase, l16, quad);
            else       ldpf<384>(pf, wtskip + (size_t)e * 98304, 0, nbase, l16, quad);
        } else {
            gemm_g<8, false>(acc, src, 264, W_pre + (size_t)(e * 3 + i) * 65536, 256, 0, 256, nbase, l16, quad);
        }
        epi(acc, b_pre + (e * 3 + i) * 256, true, dst, 264, nbase, l16, quad);
        __syncthreads();
    }
    // skip: [B, x0] -> A
    zacc(acc);
    if (PACKED) {
        gemm_pf<8, 384>(acc, xaB, 264, pf, wtskip + (size_t)e * 98304, 0, nbase, l16, quad);
        gemm_p<4, 384>(acc, x0l, 136, wtskip + (size_t)e * 98304, 256, nbase, l16, quad);
        ldpf<256>(pf, wtpost + (size_t)(e * 3) * 65536, 0, nbase, l16, quad);
    } else {
        gemm_g<8, false>(acc, xaB, 264, Wskip + (size_t)e * 93952, 256, 0,   367, nbase, l16, quad);
        gemm_g<4, true >(acc, x0l, 136, Wskip + (size_t)e * 93952, 256, 256, 367, nbase, l16, quad);
    }
    epi(acc, bskip + e * 256, true, xaA, 264, nbase, l16, quad);
    __syncthreads();
    // post0: A->B ; post1: B->A ; post2: A->B
    #pragma unroll
    for (int i = 0; i < 3; ++i) {
        const bf16* src = (i & 1) ? xaB : xaA;
        bf16*       dst = (i & 1) ? xaA : xaB;
        zacc(acc);
        if (PACKED) {
            gemm_pf<8, 256>(acc, src, 264, pf, wtpost + (size_t)(e * 3 + i) * 65536, 0, nbase, l16, quad);
            if (i < 2) ldpf<256>(pf, wtpost + (size_t)(e * 3 + i + 1) * 65536, 0, nbase, l16, quad);
            else       ldpf<256>(pf, wtf + (size_t)e * 65536, 0, nbase, l16, quad);
        } else {
            gemm_g<8, false>(acc, src, 264, W_post + (size_t)(e * 3 + i) * 65536, 256, 0, 256, nbase, l16, quad);
        }
        epi(acc, b_post + (e * 3 + i) * 256, true, dst, 264, nbase, l16, quad);
        __syncthreads();
    }
    // density = relu(xB @ Wd + bd): 16 lanes/point, shuffle(16) reduce -> f32 out
    {
        int m = t >> 4, p = t & 15;
        const bf16*  xr = xaB + (size_t)m * 264;
        const float* wd = Wd + e * 256;
        float s = 0.f;
        #pragma unroll
        for (int kk = 0; kk < 16; ++kk) s += (float)xr[p * 16 + kk] * wd[p * 16 + kk];
        s += __shfl_down(s, 8, 16);
        s += __shfl_down(s, 4, 16);
        s += __shfl_down(s, 2, 16);
        s += __shfl_down(s, 1, 16);
        if (p == 0) {
            int g = gidx[m];
            if (g >= 0) out[g] = fminf(fmaxf(s + bd[e], 0.f), 64.f);
        }
    }
    // feat = xB @ Wf + bf (no relu) -> A   (density also reads B: both reads, no barrier between)
    zacc(acc);
    if (PACKED) {
        gemm_pf<8, 256>(acc, xaB, 264, pf, wtf + (size_t)e * 65536, 0, nbase, l16, quad);
        if (wv < 4) ldpf<288>(pf, wtc1 + (size_t)e * 36864, 0, nbase, l16, quad);  // guard: nbase<128 only
    } else {
        gemm_g<8, false>(acc, xaB, 264, Wf + (size_t)e * 65536, 256, 0, 256, nbase, l16, quad);
    }
    epi(acc, bf_ + e * 256, false, xaA, 264, nbase, l16, quad);
    __syncthreads();
    // c1 = relu([A, de] @ Wc1 + bc1): 128 outputs -> waves 0..3 -> B[0..127]
    if (wv < 4) {
        zacc(acc);
        if (PACKED) {
            gemm_pf<8, 288>(acc, xaA, 264, pf, wtc1 + (size_t)e * 36864, 0, nbase, l16, quad);
            gemm_p<1, 288>(acc, del, 48,  wtc1 + (size_t)e * 36864, 256, nbase, l16, quad);
        } else {
            gemm_g<8, false>(acc, xaA, 264, Wc1 + (size_t)e * 36224, 128, 0,   283, nbase, l16, quad);
            gemm_g<1, true >(acc, del, 48,  Wc1 + (size_t)e * 36224, 128, 256, 283, nbase, l16, quad);
        }
        epi(acc, bc1 + e * 128, true, xaB, 264, nbase, l16, quad);
    }
    __syncthreads();
    // color = sigmoid(hB @ Wc2 + bc2) -> f32 out
    if (t < 96) {
        int m = t & 31, c = t >> 5;
        int g = gidx[m];
        if (g >= 0) {
            const bf16*  xr = xaB + (size_t)m * 264;
            const float* w  = Wc2 + e * 384 + c;
            float s = 0.f;
            for (int k = 0; k < 128; ++k) s += (float)xr[k] * w[k * 3];
            s += bc2[e * 3 + c];
            s = fminf(fmaxf(s, -30.f), 30.f);
            out[N_PTS + 3 * g + c] = 1.f / (1.f + expf(-s));
        }
    }
}

extern "C" void kernel_launch(void* const* d_in, const int* in_sizes, int n_in,
                              void* d_out, int out_size, void* d_ws, size_t ws_size,
                              hipStream_t stream) {
    const float* points    = (const float*)d_in[0];
    const float* viewdirs  = (const float*)d_in[1];
    const int*   aidx      = (const int*)  d_in[2];
    const float* app_embed = (const float*)d_in[3];
    const float* W0        = (const float*)d_in[4];
    const float* b0        = (const float*)d_in[5];
    const float* W_pre     = (const float*)d_in[6];
    const float* b_pre     = (const float*)d_in[7];
    const float* Wskip     = (const float*)d_in[8];
    const float* bskip     = (const float*)d_in[9];
    const float* W_post    = (const float*)d_in[10];
    const float* b_post    = (const float*)d_in[11];
    const float* Wd        = (const float*)d_in[12];
    const float* bd        = (const float*)d_in[13];
    const float* Wf        = (const float*)d_in[14];
    const float* bf_       = (const float*)d_in[15];
    const float* Wc1       = (const float*)d_in[16];
    const float* bc1       = (const float*)d_in[17];
    const float* Wc2       = (const float*)d_in[18];
    const float* bc2       = (const float*)d_in[19];
    float* out = (float*)d_out;
    (void)in_sizes; (void)n_in; (void)out_size;

    char* ws = (char*)d_ws;
    size_t off = 0;
    auto alloc = [&](size_t bytes) -> void* {
        void* p = ws + off;
        off += (bytes + 255) & ~(size_t)255;
        return p;
    };
    int*            counts  = (int*)            alloc(8 * 4);
    unsigned short* idxlist = (unsigned short*) alloc((size_t)8 * N_PTS * 2);
    bf16* wt0    = (bf16*)alloc((size_t)8  * 256 * 128 * 2);
    bf16* wtpre  = (bf16*)alloc((size_t)24 * 256 * 256 * 2);
    bf16* wtskip = (bf16*)alloc((size_t)8  * 256 * 384 * 2);
    bf16* wtpost = (bf16*)alloc((size_t)24 * 256 * 256 * 2);
    bf16* wtf    = (bf16*)alloc((size_t)8  * 256 * 256 * 2);
    bf16* wtc1   = (bf16*)alloc((size_t)8  * 128 * 288 * 2);
    const bool packed = (off <= ws_size);   // constant per-run -> graph-safe

    hipMemsetAsync(counts, 0, 8 * sizeof(int), stream);
    #define MAIN_ARGS counts, idxlist, points, viewdirs, app_embed, aidx, \
        W0, b0, W_pre, b_pre, Wskip, bskip, W_post, b_post, Wd, bd, Wf, bf_, \
        Wc1, bc1, Wc2, bc2, wt0, wtpre, wtskip, wtpost, wtf, wtc1, out
    if (packed) {
        hipLaunchKernelGGL(k_tp, dim3(384, 7), dim3(256), 0, stream,
                           W0, W_pre, Wskip, W_post, Wf, Wc1,
                           wt0, wtpre, wtskip, wtpost, wtf, wtc1,
                           points, out, counts, idxlist);
        hipLaunchKernelGGL(k_main<true>,  dim3(8 * (N_PTS / 32)), dim3(512), 0, stream, MAIN_ARGS);
    } else {
        hipLaunchKernelGGL(k_point, dim3(N_PTS / 256), dim3(256), 0, stream,
                           points, out, counts, idxlist);
        hipLaunchKernelGGL(k_main<false>, dim3(8 * (N_PTS / 32)), dim3(512), 0, stream, MAIN_ARGS);
    }
    #undef MAIN_ARGS
}

// Round 7
// 153.752 us; speedup vs baseline: 1.4470x; 1.4470x over previous
//
#include <hip/hip_runtime.h>
#include <hip/hip_bf16.h>
#include <math.h>

typedef __bf16 bf16;
typedef __bf16 bf16x4 __attribute__((ext_vector_type(4)));
typedef __bf16 bf16x8 __attribute__((ext_vector_type(8)));
typedef float  f32x4  __attribute__((ext_vector_type(4)));

#define N_PTS 32768

// ---------------- standalone per-point classify (fallback path only) ----------------
__global__ void k_point(const float* __restrict__ pts, float* __restrict__ out,
                        int* __restrict__ counts, unsigned short* __restrict__ idxlist) {
    __shared__ int lcnt[8], lbase[8];
    int t = threadIdx.x;
    int n = blockIdx.x * 256 + t;
    if (t < 8) lcnt[t] = 0;
    __syncthreads();
    float px = pts[3*n+0], py = pts[3*n+1], pz = pts[3*n+2];
    int e = 0; float best = 3.4e38f;
    #pragma unroll
    for (int i = 0; i < 4; ++i)
        #pragma unroll
        for (int j = 0; j < 2; ++j) {
            float cx = j ? 50.f : -50.f, cy = -75.f + 50.f * i;
            float dx = px - cx, dy = py - cy, dz = pz - 20.f;
            float d = dx*dx + dy*dy + dz*dz;
            if (d < best) { best = d; e = i*2 + j; }   // first-min tie-break = np argmin
        }
    bool fg = (px >= -80.f && px <= 80.f && py >= -80.f && py <= 80.f &&
               pz >= -4.f  && pz <= 44.f);
    int slot = -1;
    if (fg) {
        slot = atomicAdd(&lcnt[e], 1);          // LDS atomic: cheap
    } else {
        out[n] = 0.f;
        out[N_PTS + 3*n + 0] = 0.f;
        out[N_PTS + 3*n + 1] = 0.f;
        out[N_PTS + 3*n + 2] = 0.f;
    }
    __syncthreads();
    if (t < 8) lbase[t] = atomicAdd(&counts[t], lcnt[t]);   // 8 global atomics per block
    __syncthreads();
    if (slot >= 0) idxlist[e * N_PTS + lbase[e] + slot] = (unsigned short)n;
}

// ---------------- merged: weight pre-pack (y=0..5) + classify (y=6) ----------------
// NEW packed layout (fragment-contiguous): element (n,k) at
//   ((n>>5)*(Kpad/32) + (k>>5))*1024 + ((n>>4)&1)*512 + ((k>>3)&3)*128 + (n&15)*8 + (k&7)
// -> one wave MFMA B-load (lane=quad*16+l16, 8 elems) = ONE dense 1KB segment
//    (8 full 128B lines) instead of 16 half-used lines at 512B stride.
__global__ void k_tp(const float* __restrict__ s0, const float* __restrict__ s1,
                     const float* __restrict__ s2, const float* __restrict__ s3,
                     const float* __restrict__ s4, const float* __restrict__ s5,
                     bf16* __restrict__ d0, bf16* __restrict__ d1, bf16* __restrict__ d2,
                     bf16* __restrict__ d3, bf16* __restrict__ d4, bf16* __restrict__ d5,
                     const float* __restrict__ pts, float* __restrict__ out,
                     int* __restrict__ counts, unsigned short* __restrict__ idxlist) {
    int t = threadIdx.x;
    if (blockIdx.y == 6) {
        __shared__ int lcnt[8], lbase[8];
        if (blockIdx.x >= N_PTS / 256) return;
        int n = blockIdx.x * 256 + t;
        if (t < 8) lcnt[t] = 0;
        __syncthreads();
        float px = pts[3*n+0], py = pts[3*n+1], pz = pts[3*n+2];
        int e = 0; float best = 3.4e38f;
        #pragma unroll
        for (int i = 0; i < 4; ++i)
            #pragma unroll
            for (int j = 0; j < 2; ++j) {
                float cx = j ? 50.f : -50.f, cy = -75.f + 50.f * i;
                float dx = px - cx, dy = py - cy, dz = pz - 20.f;
                float d = dx*dx + dy*dy + dz*dz;
                if (d < best) { best = d; e = i*2 + j; }
            }
        bool fg = (px >= -80.f && px <= 80.f && py >= -80.f && py <= 80.f &&
                   pz >= -4.f  && pz <= 44.f);
        int slot = -1;
        if (fg) {
            slot = atomicAdd(&lcnt[e], 1);
        } else {
            out[n] = 0.f;
            out[N_PTS + 3*n + 0] = 0.f;
            out[N_PTS + 3*n + 1] = 0.f;
            out[N_PTS + 3*n + 2] = 0.f;
        }
        __syncthreads();
        if (t < 8) lbase[t] = atomicAdd(&counts[t], lcnt[t]);
        __syncthreads();
        if (slot >= 0) idxlist[e * N_PTS + lbase[e] + slot] = (unsigned short)n;
        return;
    }
    __shared__ bf16 tile[64 * 68];
    const float* src; bf16* dst; int K, Nn, Kpad, Eg;
    switch (blockIdx.y) {
        case 0:  src = s0; dst = d0; K = 111; Nn = 256; Kpad = 128; Eg = 8;  break; // W0
        case 1:  src = s1; dst = d1; K = 256; Nn = 256; Kpad = 256; Eg = 24; break; // W_pre
        case 2:  src = s2; dst = d2; K = 367; Nn = 256; Kpad = 384; Eg = 8;  break; // Wskip
        case 3:  src = s3; dst = d3; K = 256; Nn = 256; Kpad = 256; Eg = 24; break; // W_post
        case 4:  src = s4; dst = d4; K = 256; Nn = 256; Kpad = 256; Eg = 8;  break; // Wf
        default: src = s5; dst = d5; K = 283; Nn = 128; Kpad = 288; Eg = 8;  break; // Wc1
    }
    int ktiles = (Kpad + 63) / 64, ntiles = Nn / 64;
    int b = blockIdx.x;
    if (b >= Eg * ktiles * ntiles) return;
    int eg = b / (ktiles * ntiles), rem = b % (ktiles * ntiles);
    int kt = rem / ntiles, nt = rem % ntiles;
    #pragma unroll
    for (int r = 0; r < 4; ++r) {
        int idx = r * 256 + t;
        int kl = idx >> 4, nl4 = (idx & 15) * 4;
        int kg = kt * 64 + kl, ng = nt * 64 + nl4;
        bf16x4 v = (bf16x4){(bf16)0.f, (bf16)0.f, (bf16)0.f, (bf16)0.f};
        if (kg < K) {
            f32x4 f = *(const f32x4*)(src + ((size_t)(eg * K + kg)) * Nn + ng);
            v[0] = (bf16)f[0]; v[1] = (bf16)f[1]; v[2] = (bf16)f[2]; v[3] = (bf16)f[3];
        }
        *(bf16x4*)(&tile[kl * 68 + nl4]) = v;
    }
    __syncthreads();
    #pragma unroll
    for (int i = 0; i < 2; ++i) {
        int idx = i * 256 + t;
        int ng_l = idx >> 3, kq = idx & 7;
        int kg = kt * 64 + kq * 8, ng = nt * 64 + ng_l;
        if (kg < Kpad) {
            bf16x8 v;
            #pragma unroll
            for (int j = 0; j < 8; ++j) v[j] = tile[(kq * 8 + j) * 68 + ng_l];
            size_t off = ((size_t)(ng >> 5) * (Kpad >> 5) + (size_t)(kg >> 5)) * 1024
                       + (size_t)((ng >> 4) & 1) * 512
                       + (size_t)((kg >> 3) & 3) * 128
                       + (size_t)(ng & 15) * 8;
            *(bf16x8*)(dst + (size_t)eg * Nn * Kpad + off) = v;
        }
    }
}

// ---------------- fused MLP: 32 pts/block, 512 threads (8 waves x n=32), MFMA 16x16x32 ----------------
__device__ __forceinline__ f32x4 mfma16(bf16x8 a, bf16x8 b, f32x4 c) {
    return __builtin_amdgcn_mfma_f32_16x16x32_bf16(a, b, c, 0, 0, 0);
}

__device__ __forceinline__ void zacc(f32x4 acc[2][2]) {
    #pragma unroll
    for (int i = 0; i < 2; ++i)
        #pragma unroll
        for (int j = 0; j < 2; ++j) acc[i][j] = (f32x4){0.f, 0.f, 0.f, 0.f};
}

// PACKED: fragment-contiguous B. Per-lane data identical to the row-major layout
// (lane quad*16+l16 gets row nbase+half*16+l16, k=s*32+quad*8+j) -- only the
// ADDRESSES changed: each wave load is one dense 1KB segment, and the NS loads
// of a layer walk a contiguous NS*2KB region.
template<int NS, int KPAD>
__device__ __forceinline__ void gemm_p(f32x4 acc[2][2], const bf16* A, int astr,
                                       const bf16* __restrict__ Wt, int wk0,
                                       int nbase, int l16, int quad, int lane) {
    const bf16* bp = Wt + ((size_t)(nbase >> 5) * (KPAD >> 5) + (size_t)(wk0 >> 5)) * 1024
                   + (size_t)lane * 8;
    #pragma unroll
    for (int s = 0; s < NS; ++s) {
        int kA = s * 32 + quad * 8;
        bf16x8 a0 = *(const bf16x8*)(A + (size_t)(l16)      * astr + kA);
        bf16x8 a1 = *(const bf16x8*)(A + (size_t)(16 + l16) * astr + kA);
        bf16x8 b0 = *(const bf16x8*)(bp + s * 1024);         // rows nbase..+15
        bf16x8 b1 = *(const bf16x8*)(bp + s * 1024 + 512);   // rows nbase+16..+31
        acc[0][0] = mfma16(a0, b0, acc[0][0]);
        acc[1][0] = mfma16(a1, b0, acc[1][0]);
        acc[0][1] = mfma16(a0, b1, acc[0][1]);
        acc[1][1] = mfma16(a1, b1, acc[1][1]);
    }
}

// DIRECT fallback (ws too small): strided f32 loads
template<int NS, bool GUARD>
__device__ __forceinline__ void gemm_g(f32x4 acc[2][2], const bf16* A, int astr,
                                       const float* __restrict__ W, int ldn, int wk0, int Klim,
                                       int nbase, int l16, int quad) {
    #pragma unroll
    for (int s = 0; s < NS; ++s) {
        int kA = s * 32 + quad * 8;
        bf16x8 a0 = *(const bf16x8*)(A + (size_t)(l16)      * astr + kA);
        bf16x8 a1 = *(const bf16x8*)(A + (size_t)(16 + l16) * astr + kA);
        #pragma unroll
        for (int nt = 0; nt < 2; ++nt) {
            int n = nbase + nt * 16 + l16;
            const float* wp = W + (size_t)(wk0 + kA) * ldn + n;
            bf16x8 b;
            #pragma unroll
            for (int j = 0; j < 8; ++j) {
                float wv = 0.f;
                if (!GUARD || (wk0 + kA + j < Klim)) wv = wp[(size_t)j * ldn];
                b[j] = (bf16)wv;
            }
            acc[0][nt] = mfma16(a0, b, acc[0][nt]);
            acc[1][nt] = mfma16(a1, b, acc[1][nt]);
        }
    }
}

__device__ __forceinline__ void epi(f32x4 acc[2][2], const float* bias, bool dorelu,
                                    bf16* dst, int dstr, int nbase, int l16, int quad) {
    #pragma unroll
    for (int nt = 0; nt < 2; ++nt) {
        float bv = bias[nbase + nt * 16 + l16];
        #pragma unroll
        for (int mt = 0; mt < 2; ++mt) {
            #pragma unroll
            for (int r = 0; r < 4; ++r) {
                float v = acc[mt][nt][r] + bv;
                v = fminf(fmaxf(v, -64.f), 64.f);
                if (dorelu) v = fmaxf(v, 0.f);
                // C/D layout: col(n)=lane&15, row(m)=quad*4+r  [measured m89/m91]
                dst[(size_t)(mt * 16 + quad * 4 + r) * dstr + nbase + nt * 16 + l16] = (bf16)v;
            }
        }
    }
}

template<bool PACKED>
__global__ __launch_bounds__(512, 2)
void k_main(const int* __restrict__ counts, const unsigned short* __restrict__ idxlist,
            const float* __restrict__ pts, const float* __restrict__ dirs,
            const float* __restrict__ app_embed, const int* __restrict__ aidx,
            const float* __restrict__ W0, const float* __restrict__ b0,
            const float* __restrict__ W_pre, const float* __restrict__ b_pre,
            const float* __restrict__ Wskip, const float* __restrict__ bskip,
            const float* __restrict__ W_post, const float* __restrict__ b_post,
            const float* __restrict__ Wd, const float* __restrict__ bd,
            const float* __restrict__ Wf, const float* __restrict__ bf_,
            const float* __restrict__ Wc1, const float* __restrict__ bc1,
            const float* __restrict__ Wc2, const float* __restrict__ bc2,
            const bf16* __restrict__ wt0, const bf16* __restrict__ wtpre,
            const bf16* __restrict__ wtskip, const bf16* __restrict__ wtpost,
            const bf16* __restrict__ wtf, const bf16* __restrict__ wtc1,
            float* __restrict__ out) {
    __shared__ bf16 xaA[32 * 264];
    __shared__ bf16 xaB[32 * 264];
    __shared__ bf16 x0l[32 * 136];
    __shared__ bf16 del[32 * 48];
    __shared__ int  gidx[32];
    __shared__ int  aid[32];

    const int e    = blockIdx.x & 7;       // expert -> XCD affinity (per-expert 1.23 MB packed weights L2-resident)
    const int tile = blockIdx.x >> 3;
    const int cnt  = counts[e];
    if (tile * 32 >= cnt) return;
    const int t = threadIdx.x;
    const int lane = t & 63, wv = t >> 6;          // 8 waves
    const int l16 = lane & 15, quad = lane >> 4;
    const int nbase = wv * 32;                     // 32 outputs per wave

    if (t < 32) {
        int i = tile * 32 + t;
        int g = (i < cnt) ? (int)idxlist[e * N_PTS + i] : -1;
        gidx[t] = g;
        aid[t]  = (g >= 0) ? aidx[g] : 0;
    }
    __syncthreads();
    { // stage x0 = [p(3), posenc(60), app(48), 0-pad->128] and de = [d(3), posenc(24), 0-pad->32]
        int row = t >> 4, c0 = t & 15, g = gidx[row];
        float p0 = 0.f, p1 = 0.f, p2 = 0.f, q0 = 0.f, q1 = 0.f, q2 = 0.f;
        if (g >= 0) {
            p0 = pts[3*g+0];  p1 = pts[3*g+1];  p2 = pts[3*g+2];
            q0 = dirs[3*g+0]; q1 = dirs[3*g+1]; q2 = dirs[3*g+2];
        }
        int ai = aid[row];
        #pragma unroll
        for (int i = 0; i < 8; ++i) {
            int col = c0 + 16 * i;             // 0..127
            float v = 0.f;
            if (g >= 0 && col < 111) {
                if (col < 3) {
                    v = (col == 0) ? p0 : (col == 1) ? p1 : p2;
                } else if (col < 63) {
                    int q = col - 3, fi = q / 6, d = q % 6, ax = (d < 3) ? d : (d - 3);
                    float p = (ax == 0) ? p0 : (ax == 1) ? p1 : p2;
                    float f = (float)exp2((double)fi * (10.0 / 9.0)); // np 2**linspace(0,10,10)
                    v = (d < 3) ? sinf(f * p) : cosf(f * p);
                } else {
                    v = app_embed[((size_t)(e * 1000 + ai)) * 48 + (col - 63)];
                }
            }
            x0l[row * 136 + col] = (bf16)v;
        }
        #pragma unroll
        for (int i = 0; i < 2; ++i) {
            int col = c0 + 16 * i;             // 0..31
            float v = 0.f;
            if (g >= 0 && col < 27) {
                if (col < 3) {
                    v = (col == 0) ? q0 : (col == 1) ? q1 : q2;
                } else {
                    int q = col - 3, fi = q / 6, d = q % 6, ax = (d < 3) ? d : (d - 3);
                    float p = (ax == 0) ? q0 : (ax == 1) ? q1 : q2;
                    float f = (float)exp2((double)fi * (4.0 / 3.0));  // np 2**linspace(0,4,4)
                    v = (d < 3) ? sinf(f * p) : cosf(f * p);
                }
            }
            del[row * 48 + col] = (bf16)v;
        }
    }
    __syncthreads();

    f32x4 acc[2][2];
    // L0: x0 -> xaA
    zacc(acc);
    if (PACKED) gemm_p<4, 128>(acc, x0l, 136, wt0 + (size_t)e * 32768, 0, nbase, l16, quad, lane);
    else        gemm_g<4, true>(acc, x0l, 136, W0 + (size_t)e * 28416, 256, 0, 111, nbase, l16, quad);
    epi(acc, b0 + e * 256, true, xaA, 264, nbase, l16, quad);
    __syncthreads();
    // pre0: A->B ; pre1: B->A ; pre2: A->B
    #pragma unroll
    for (int i = 0; i < 3; ++i) {
        const bf16* src = (i & 1) ? xaB : xaA;
        bf16*       dst = (i & 1) ? xaA : xaB;
        zacc(acc);
        if (PACKED) gemm_p<8, 256>(acc, src, 264, wtpre + (size_t)(e * 3 + i) * 65536, 0, nbase, l16, quad, lane);
        else        gemm_g<8, false>(acc, src, 264, W_pre + (size_t)(e * 3 + i) * 65536, 256, 0, 256, nbase, l16, quad);
        epi(acc, b_pre + (e * 3 + i) * 256, true, dst, 264, nbase, l16, quad);
        __syncthreads();
    }
    // skip: [B, x0] -> A
    zacc(acc);
    if (PACKED) {
        gemm_p<8, 384>(acc, xaB, 264, wtskip + (size_t)e * 98304, 0,   nbase, l16, quad, lane);
        gemm_p<4, 384>(acc, x0l, 136, wtskip + (size_t)e * 98304, 256, nbase, l16, quad, lane);
    } else {
        gemm_g<8, false>(acc, xaB, 264, Wskip + (size_t)e * 93952, 256, 0,   367, nbase, l16, quad);
        gemm_g<4, true >(acc, x0l, 136, Wskip + (size_t)e * 93952, 256, 256, 367, nbase, l16, quad);
    }
    epi(acc, bskip + e * 256, true, xaA, 264, nbase, l16, quad);
    __syncthreads();
    // post0: A->B ; post1: B->A ; post2: A->B
    #pragma unroll
    for (int i = 0; i < 3; ++i) {
        const bf16* src = (i & 1) ? xaB : xaA;
        bf16*       dst = (i & 1) ? xaA : xaB;
        zacc(acc);
        if (PACKED) gemm_p<8, 256>(acc, src, 264, wtpost + (size_t)(e * 3 + i) * 65536, 0, nbase, l16, quad, lane);
        else        gemm_g<8, false>(acc, src, 264, W_post + (size_t)(e * 3 + i) * 65536, 256, 0, 256, nbase, l16, quad);
        epi(acc, b_post + (e * 3 + i) * 256, true, dst, 264, nbase, l16, quad);
        __syncthreads();
    }
    // density = relu(xB @ Wd + bd): 16 lanes/point, shuffle(16) reduce -> f32 out
    {
        int m = t >> 4, p = t & 15;
        const bf16*  xr = xaB + (size_t)m * 264;
        const float* wd = Wd + e * 256;
        float s = 0.f;
        #pragma unroll
        for (int kk = 0; kk < 16; ++kk) s += (float)xr[p * 16 + kk] * wd[p * 16 + kk];
        s += __shfl_down(s, 8, 16);
        s += __shfl_down(s, 4, 16);
        s += __shfl_down(s, 2, 16);
        s += __shfl_down(s, 1, 16);
        if (p == 0) {
            int g = gidx[m];
            if (g >= 0) out[g] = fminf(fmaxf(s + bd[e], 0.f), 64.f);
        }
    }
    // feat = xB @ Wf + bf (no relu) -> A   (density also reads B: both reads, no barrier between)
    zacc(acc);
    if (PACKED) gemm_p<8, 256>(acc, xaB, 264, wtf + (size_t)e * 65536, 0, nbase, l16, quad, lane);
    else        gemm_g<8, false>(acc, xaB, 264, Wf + (size_t)e * 65536, 256, 0, 256, nbase, l16, quad);
    epi(acc, bf_ + e * 256, false, xaA, 264, nbase, l16, quad);
    __syncthreads();
    // c1 = relu([A, de] @ Wc1 + bc1): 128 outputs -> waves 0..3 -> B[0..127]
    if (wv < 4) {
        zacc(acc);
        if (PACKED) {
            gemm_p<8, 288>(acc, xaA, 264, wtc1 + (size_t)e * 36864, 0,   nbase, l16, quad, lane);
            gemm_p<1, 288>(acc, del, 48,  wtc1 + (size_t)e * 36864, 256, nbase, l16, quad, lane);
        } else {
            gemm_g<8, false>(acc, xaA, 264, Wc1 + (size_t)e * 36224, 128, 0,   283, nbase, l16, quad);
            gemm_g<1, true >(acc, del, 48,  Wc1 + (size_t)e * 36224, 128, 256, 283, nbase, l16, quad);
        }
        epi(acc, bc1 + e * 128, true, xaB, 264, nbase, l16, quad);
    }
    __syncthreads();
    // color = sigmoid(hB @ Wc2 + bc2) -> f32 out
    if (t < 96) {
        int m = t & 31, c = t >> 5;
        int g = gidx[m];
        if (g >= 0) {
            const bf16*  xr = xaB + (size_t)m * 264;
            const float* w  = Wc2 + e * 384 + c;
            float s = 0.f;
            for (int k = 0; k < 128; ++k) s += (float)xr[k] * w[k * 3];
            s += bc2[e * 3 + c];
            s = fminf(fmaxf(s, -30.f), 30.f);
            out[N_PTS + 3 * g + c] = 1.f / (1.f + expf(-s));
        }
    }
}

extern "C" void kernel_launch(void* const* d_in, const int* in_sizes, int n_in,
                              void* d_out, int out_size, void* d_ws, size_t ws_size,
                              hipStream_t stream) {
    const float* points    = (const float*)d_in[0];
    const float* viewdirs  = (const float*)d_in[1];
    const int*   aidx      = (const int*)  d_in[2];
    const float* app_embed = (const float*)d_in[3];
    const float* W0        = (const float*)d_in[4];
    const float* b0        = (const float*)d_in[5];
    const float* W_pre     = (const float*)d_in[6];
    const float* b_pre     = (const float*)d_in[7];
    const float* Wskip     = (const float*)d_in[8];
    const float* bskip     = (const float*)d_in[9];
    const float* W_post    = (const float*)d_in[10];
    const float* b_post    = (const float*)d_in[11];
    const float* Wd        = (const float*)d_in[12];
    const float* bd        = (const float*)d_in[13];
    const float* Wf        = (const float*)d_in[14];
    const float* bf_       = (const float*)d_in[15];
    const float* Wc1       = (const float*)d_in[16];
    const float* bc1       = (const float*)d_in[17];
    const float* Wc2       = (const float*)d_in[18];
    const float* bc2       = (const float*)d_in[19];
    float* out = (float*)d_out;
    (void)in_sizes; (void)n_in; (void)out_size;

    char* ws = (char*)d_ws;
    size_t off = 0;
    auto alloc = [&](size_t bytes) -> void* {
        void* p = ws + off;
        off += (bytes + 255) & ~(size_t)255;
        return p;
    };
    int*            counts  = (int*)            alloc(8 * 4);
    unsigned short* idxlist = (unsigned short*) alloc((size_t)8 * N_PTS * 2);
    bf16* wt0    = (bf16*)alloc((size_t)8  * 256 * 128 * 2);
    bf16* wtpre  = (bf16*)alloc((size_t)24 * 256 * 256 * 2);
    bf16* wtskip = (bf16*)alloc((size_t)8  * 256 * 384 * 2);
    bf16* wtpost = (bf16*)alloc((size_t)24 * 256 * 256 * 2);
    bf16* wtf    = (bf16*)alloc((size_t)8  * 256 * 256 * 2);
    bf16* wtc1   = (bf16*)alloc((size_t)8  * 128 * 288 * 2);
    const bool packed = (off <= ws_size);   // constant per-run -> graph-safe

    hipMemsetAsync(counts, 0, 8 * sizeof(int), stream);
    #define MAIN_ARGS counts, idxlist, points, viewdirs, app_embed, aidx, \
        W0, b0, W_pre, b_pre, Wskip, bskip, W_post, b_post, Wd, bd, Wf, bf_, \
        Wc1, bc1, Wc2, bc2, wt0, wtpre, wtskip, wtpost, wtf, wtc1, out
    if (packed) {
        hipLaunchKernelGGL(k_tp, dim3(384, 7), dim3(256), 0, stream,
                           W0, W_pre, Wskip, W_post, Wf, Wc1,
                           wt0, wtpre, wtskip, wtpost, wtf, wtc1,
                           points, out, counts, idxlist);
        hipLaunchKernelGGL(k_main<true>,  dim3(8 * (N_PTS / 32)), dim3(512), 0, stream, MAIN_ARGS);
    } else {
        hipLaunchKernelGGL(k_point, dim3(N_PTS / 256), dim3(256), 0, stream,
                           points, out, counts, idxlist);
        hipLaunchKernelGGL(k_main<false>, dim3(8 * (N_PTS / 32)), dim3(512), 0, stream, MAIN_ARGS);
    }
    #undef MAIN_ARGS
}